// Round 1
// baseline (472.479 us; speedup 1.0000x reference)
//
#include <hip/hip_runtime.h>
#include <math.h>

#define B_ 32
#define W_ 512
#define H_ 768
#define HH_ 384
#define E_ 128
#define R_ 1024
#define BE_ (B_*E_)     /* 4096 entity slots */
#define K1_ (2*H_)      /* 1536 */

// ---------------------------------------------------------------------------
// Kernel 1: gather per-entity input reprs  X[b*E+e] = [hs[b,start], emb[label]]
// ---------------------------------------------------------------------------
__global__ __launch_bounds__(192) void build_x_kernel(
    const float* __restrict__ hs, const int* __restrict__ ent_start,
    const int* __restrict__ ent_label, const float* __restrict__ emb,
    float* __restrict__ X)
{
    int be = blockIdx.x;           // 0..4095
    int b  = be >> 7;              // E_=128
    int start = ent_start[be];
    int label = ent_label[be];
    const float4* s0 = (const float4*)(hs + ((size_t)b * W_ + start) * H_);
    const float4* s1 = (const float4*)(emb + (size_t)label * H_);
    float4* dst = (float4*)(X + (size_t)be * K1_);
    int i = threadIdx.x;           // 192 == H_/4
    dst[i]          = s0[i];
    dst[H_/4 + i]   = s1[i];
}

// ---------------------------------------------------------------------------
// Kernel 2: generic fp32 tiled GEMM  C[M,N] = act(A[M,K] @ Wt[N,K]^T + bias)
// 64x64 tile, BK=16, 256 threads, 4x4 microtile per thread.
// ---------------------------------------------------------------------------
#define BM 64
#define BN 64
#define BK 16
__global__ __launch_bounds__(256) void gemm_bias_act(
    const float* __restrict__ A, const float* __restrict__ Wt,
    const float* __restrict__ bias, float* __restrict__ C,
    int M, int N, int K, int do_relu)
{
    __shared__ float As[BK][BM + 4];
    __shared__ float Ws[BK][BN + 4];
    const int bm = blockIdx.y * BM;
    const int bn = blockIdx.x * BN;
    const int tid  = threadIdx.x;
    const int tx   = tid & 15;
    const int ty   = tid >> 4;
    const int lrow = tid >> 2;            // 0..63
    const int lcol = (tid & 3) * 4;       // 0,4,8,12

    float acc[4][4];
#pragma unroll
    for (int i = 0; i < 4; ++i)
#pragma unroll
        for (int j = 0; j < 4; ++j) acc[i][j] = 0.f;

    const float* Aptr = A  + (size_t)(bm + lrow) * K + lcol;
    const float* Wptr = Wt + (size_t)(bn + lrow) * K + lcol;

    for (int k0 = 0; k0 < K; k0 += BK) {
        float4 av = *(const float4*)(Aptr + k0);
        float4 wv = *(const float4*)(Wptr + k0);
        As[lcol+0][lrow] = av.x; As[lcol+1][lrow] = av.y;
        As[lcol+2][lrow] = av.z; As[lcol+3][lrow] = av.w;
        Ws[lcol+0][lrow] = wv.x; Ws[lcol+1][lrow] = wv.y;
        Ws[lcol+2][lrow] = wv.z; Ws[lcol+3][lrow] = wv.w;
        __syncthreads();
#pragma unroll
        for (int kk = 0; kk < BK; ++kk) {
            float a[4], w[4];
#pragma unroll
            for (int i = 0; i < 4; ++i) a[i] = As[kk][ty*4 + i];
#pragma unroll
            for (int j = 0; j < 4; ++j) w[j] = Ws[kk][tx*4 + j];
#pragma unroll
            for (int i = 0; i < 4; ++i)
#pragma unroll
                for (int j = 0; j < 4; ++j)
                    acc[i][j] = fmaf(a[i], w[j], acc[i][j]);
        }
        __syncthreads();
    }

#pragma unroll
    for (int i = 0; i < 4; ++i) {
        int rowi = bm + ty*4 + i;
#pragma unroll
        for (int j = 0; j < 4; ++j) {
            int colj = bn + tx*4 + j;
            float v = acc[i][j];
            if (bias) v += bias[colj];
            if (do_relu) v = fmaxf(v, 0.f);
            C[(size_t)rowi * N + colj] = v;
        }
    }
}

// ---------------------------------------------------------------------------
// Kernel 3: per-entity linear terms  linHT[be] = {h.Wlin0h, h.Wlin1h, t.Wlin0t, t.Wlin1t}
// ---------------------------------------------------------------------------
__global__ __launch_bounds__(128) void lin_parts_kernel(
    const float* __restrict__ Hh, const float* __restrict__ Ht,
    const float* __restrict__ W_lin, float* __restrict__ linHT)
{
    int be   = blockIdx.x;
    int wid  = threadIdx.x >> 6;   // 0: head part, 1: tail part
    int lane = threadIdx.x & 63;
    const float* src = (wid == 0 ? Hh : Ht) + (size_t)be * HH_;
    const float* wl0 = W_lin + (wid == 0 ? 0 : HH_);          // W_lin[0, off..]
    const float* wl1 = W_lin + 2*HH_ + (wid == 0 ? 0 : HH_);  // W_lin[1, off..]
    float s0 = 0.f, s1 = 0.f;
#pragma unroll
    for (int t = 0; t < HH_/64; ++t) {
        int i = lane + t*64;
        float v = src[i];
        s0 += v * wl0[i];
        s1 += v * wl1[i];
    }
#pragma unroll
    for (int off = 32; off; off >>= 1) {
        s0 += __shfl_down(s0, off);
        s1 += __shfl_down(s1, off);
    }
    if (lane == 0) {
        linHT[be*4 + wid*2 + 0] = s0;
        linHT[be*4 + wid*2 + 1] = s1;
    }
}

// ---------------------------------------------------------------------------
// Kernel 4: zero the scalar output
// ---------------------------------------------------------------------------
__global__ void zero_out_kernel(float* __restrict__ out)
{
    if (threadIdx.x == 0) out[0] = 0.f;
}

// ---------------------------------------------------------------------------
// Kernel 5: per-relation logits + CE, accumulate loss
// one wave per relation (grid-strided); block reduce; 1 atomic per block
// ---------------------------------------------------------------------------
__global__ __launch_bounds__(256) void relation_loss_kernel(
    const int* __restrict__ rel_head, const int* __restrict__ rel_tail,
    const int* __restrict__ rel_label,
    const float* __restrict__ Hh, const float* __restrict__ U,
    const float* __restrict__ linHT, const float* __restrict__ b_lin,
    float* __restrict__ out)
{
    const int NWAVE = gridDim.x * 4;
    int wave = blockIdx.x * 4 + (threadIdx.x >> 6);
    int lane = threadIdx.x & 63;
    float bl0 = b_lin[0], bl1 = b_lin[1];
    float acc = 0.f;

    for (int rel = wave; rel < B_*R_; rel += NWAVE) {
        int b  = rel >> 10;                 // R_=1024
        int rh = rel_head[rel];
        int rt = rel_tail[rel];
        int lab = rel_label[rel];
        const float* h = Hh + (size_t)(b*E_ + rh) * HH_;
        const float* u = U  + (size_t)(b*E_ + rt) * (2*HH_);
        float s0 = 0.f, s1 = 0.f;
#pragma unroll
        for (int t = 0; t < HH_/64; ++t) {
            int i = lane + t*64;
            float hv = h[i];
            s0 += hv * u[i];
            s1 += hv * u[HH_ + i];
        }
#pragma unroll
        for (int off = 32; off; off >>= 1) {
            s0 += __shfl_down(s0, off);
            s1 += __shfl_down(s1, off);
        }
        if (lane == 0) {
            int ih = (b*E_ + rh) * 4, it = (b*E_ + rt) * 4;
            float l0 = s0 + linHT[ih + 0] + linHT[it + 2] + bl0;
            float l1 = s1 + linHT[ih + 1] + linHT[it + 3] + bl1;
            float m = fmaxf(l0, l1);
            float lse = m + logf(expf(l0 - m) + expf(l1 - m));
            acc += lse - (lab == 0 ? l0 : l1);
        }
    }

    __shared__ float red[4];
    if (lane == 0) red[threadIdx.x >> 6] = acc;
    __syncthreads();
    if (threadIdx.x == 0)
        atomicAdd(out, (red[0] + red[1] + red[2] + red[3]) * (1.0f / R_));
}

// ---------------------------------------------------------------------------
extern "C" void kernel_launch(void* const* d_in, const int* in_sizes, int n_in,
                              void* d_out, int out_size, void* d_ws, size_t ws_size,
                              hipStream_t stream)
{
    const float* hs        = (const float*)d_in[0];
    const int*   rel_head  = (const int*)  d_in[1];
    const int*   rel_tail  = (const int*)  d_in[2];
    const int*   rel_label = (const int*)  d_in[3];
    const int*   ent_start = (const int*)  d_in[4];
    /* d_in[5] entities_end: unused by reference */
    const int*   ent_label = (const int*)  d_in[6];
    const float* emb   = (const float*)d_in[7];
    const float* Wh1   = (const float*)d_in[8];
    const float* bh1   = (const float*)d_in[9];
    const float* Wh2   = (const float*)d_in[10];
    const float* bh2   = (const float*)d_in[11];
    const float* Wt1   = (const float*)d_in[12];
    const float* bt1   = (const float*)d_in[13];
    const float* Wt2   = (const float*)d_in[14];
    const float* bt2   = (const float*)d_in[15];
    const float* W_bil = (const float*)d_in[16];
    const float* W_lin = (const float*)d_in[17];
    const float* b_lin = (const float*)d_in[18];
    float* out = (float*)d_out;
    float* ws  = (float*)d_ws;

    // workspace layout (floats)
    float* X     = ws;                              // 4096*1536 = 6291456
    float* H1h   = X    + (size_t)BE_ * K1_;        // 4096*768
    float* H1t   = H1h  + (size_t)BE_ * H_;         // 4096*768
    float* Hh    = H1t  + (size_t)BE_ * H_;         // 4096*384
    float* Ht    = Hh   + (size_t)BE_ * HH_;        // 4096*384
    float* linHT = Ht   + (size_t)BE_ * HH_;        // 4096*4
    float* U     = X;   // reuse X after layer-1 GEMMs (4096*768 < 4096*1536)

    dim3 blk(256);

    // 1) gather entity inputs
    build_x_kernel<<<dim3(BE_), dim3(192), 0, stream>>>(hs, ent_start, ent_label, emb, X);

    // 2) layer-1 FFNN GEMMs (head & tail nets): [4096,1536] @ [768,1536]^T
    dim3 g1(H_/BN, BE_/BM);
    gemm_bias_act<<<g1, blk, 0, stream>>>(X, Wh1, bh1, H1h, BE_, H_, K1_, 1);
    gemm_bias_act<<<g1, blk, 0, stream>>>(X, Wt1, bt1, H1t, BE_, H_, K1_, 1);

    // 3) layer-2 FFNN GEMMs: [4096,768] @ [384,768]^T
    dim3 g2(HH_/BN, BE_/BM);
    gemm_bias_act<<<g2, blk, 0, stream>>>(H1h, Wh2, bh2, Hh, BE_, HH_, H_, 1);
    gemm_bias_act<<<g2, blk, 0, stream>>>(H1t, Wt2, bt2, Ht, BE_, HH_, H_, 1);

    // 4) bilinear precompute: U[be, o*384+i] = sum_j W_bil[o,i,j] * Ht[be,j]
    //    (W_bil flat [2,384,384] is exactly a [768,384] row-major weight)
    dim3 g3(2*HH_/BN, BE_/BM);
    gemm_bias_act<<<g3, blk, 0, stream>>>(Ht, W_bil, (const float*)nullptr, U, BE_, 2*HH_, HH_, 0);

    // 5) per-entity linear terms
    lin_parts_kernel<<<dim3(BE_), dim3(128), 0, stream>>>(Hh, Ht, W_lin, linHT);

    // 6) loss
    zero_out_kernel<<<dim3(1), dim3(64), 0, stream>>>(out);
    relation_loss_kernel<<<dim3(512), blk, 0, stream>>>(
        rel_head, rel_tail, rel_label, Hh, U, linHT, b_lin, out);
}

// Round 2
// 107.456 us; speedup vs baseline: 4.3970x; 4.3970x over previous
//
#include <hip/hip_runtime.h>
#include <math.h>

typedef unsigned short u16;
typedef __bf16 bf16x8 __attribute__((ext_vector_type(8)));
typedef float f32x4 __attribute__((ext_vector_type(4)));

#define B_ 32
#define W_ 512
#define H_ 768
#define HH_ 384
#define E_ 128
#define R_ 1024
#define BE_ (B_*E_)     /* 4096 */
#define K1_ (2*H_)      /* 1536 */

__device__ __forceinline__ u16 f2bf(float f) {
  unsigned u = __float_as_uint(f);
  u = (u + 0x7fffu + ((u >> 16) & 1u)) >> 16;   // RNE
  return (u16)u;
}
__device__ __forceinline__ float bf2f(u16 u) {
  return __uint_as_float(((unsigned)u) << 16);
}

__device__ __forceinline__ void gload_lds16(const void* g, void* l) {
  __builtin_amdgcn_global_load_lds(
      (__attribute__((address_space(1))) void*)(g),
      (__attribute__((address_space(3))) void*)(l), 16, 0, 0);
}

// ---------------------------------------------------------------------------
// prep: convert all weights to bf16 (concatenated) + concat biases (fp32)
// segments in float4 units
// ---------------------------------------------------------------------------
__global__ __launch_bounds__(256) void prep_weights(
    const float* __restrict__ Wh1, const float* __restrict__ Wt1,
    const float* __restrict__ Wh2, const float* __restrict__ Wt2,
    const float* __restrict__ Wbil,
    const float* __restrict__ bh1, const float* __restrict__ bt1,
    const float* __restrict__ bh2, const float* __restrict__ bt2,
    u16* __restrict__ W1c, u16* __restrict__ W2c, u16* __restrict__ Wb,
    float* __restrict__ bcat1, float* __restrict__ b2cat)
{
  const int i = blockIdx.x * 256 + threadIdx.x;
  const int S0 = 294912;            // Wh1: 768*1536/4
  const int S1 = S0 + 294912;       // Wt1
  const int S2 = S1 + 73728;        // Wh2: 384*768/4
  const int S3 = S2 + 73728;        // Wt2
  const int S4 = S3 + 73728;        // Wbil: 2*384*384/4
  const int S5 = S4 + 384;          // bcat1: 1536/4
  const int S6 = S5 + 192;          // b2cat: 768/4

  if (i < S4) {
    const float* src; u16* dst; int j;
    if (i < S0)      { src = Wh1;  dst = W1c;           j = i; }
    else if (i < S1) { src = Wt1;  dst = W1c + 1179648; j = i - S0; }
    else if (i < S2) { src = Wh2;  dst = W2c;           j = i - S1; }
    else if (i < S3) { src = Wt2;  dst = W2c + 294912;  j = i - S2; }
    else             { src = Wbil; dst = Wb;            j = i - S3; }
    float4 v = ((const float4*)src)[j];
    ushort4 o;
    o.x = f2bf(v.x); o.y = f2bf(v.y); o.z = f2bf(v.z); o.w = f2bf(v.w);
    ((ushort4*)dst)[j] = o;
  } else if (i < S5) {
    int j = i - S4;
    ((float4*)bcat1)[j] = (j < 192) ? ((const float4*)bh1)[j]
                                    : ((const float4*)bt1)[j - 192];
  } else if (i < S6) {
    int j = i - S5;
    ((float4*)b2cat)[j] = (j < 96) ? ((const float4*)bh2)[j]
                                   : ((const float4*)bt2)[j - 96];
  }
}

// ---------------------------------------------------------------------------
// gather entity inputs to bf16:  X[b*E+e] = [hs[b,start,:], emb[label,:]]
// ---------------------------------------------------------------------------
__global__ __launch_bounds__(192) void build_x_kernel(
    const float* __restrict__ hs, const int* __restrict__ ent_start,
    const int* __restrict__ ent_label, const float* __restrict__ emb,
    u16* __restrict__ X)
{
  int be = blockIdx.x;           // 0..4095
  int b  = be >> 7;
  int start = ent_start[be];
  int label = ent_label[be];
  const float4* s0 = (const float4*)(hs + ((size_t)b * W_ + start) * H_);
  const float4* s1 = (const float4*)(emb + (size_t)label * H_);
  ushort4* dst = (ushort4*)(X + (size_t)be * K1_);
  int i = threadIdx.x;           // 192 == H_/4
  float4 v0 = s0[i], v1 = s1[i];
  ushort4 o0, o1;
  o0.x = f2bf(v0.x); o0.y = f2bf(v0.y); o0.z = f2bf(v0.z); o0.w = f2bf(v0.w);
  o1.x = f2bf(v1.x); o1.y = f2bf(v1.y); o1.z = f2bf(v1.z); o1.w = f2bf(v1.w);
  dst[i]           = o0;
  dst[H_/4 + i]    = o1;
}

// ---------------------------------------------------------------------------
// bf16 MFMA GEMM: C[M,N] = act(A[M,K(lda)] @ Wt[N,K]^T + bias)
// 128x128 tile, BK=64, 256 threads (4 waves, 2x2 wave grid, 64x64 per wave).
// global_load_lds(16B) staging, linear LDS + pre-swizzled source:
//   LDS(row, slot) holds global k-chunk (slot ^ (row&7)); read with same XOR.
// half_n/aoff: for col-block bn >= half_n, A is offset by aoff elements
// (fused head/tail layer-2).
// ---------------------------------------------------------------------------
#define BM 128
#define BN 128
#define BKK 64

__global__ __launch_bounds__(256, 2) void gemm_bf16(
    const u16* __restrict__ A, int lda,
    const u16* __restrict__ Wt,              // [N][K] row-major
    const float* __restrict__ bias,
    u16* __restrict__ C, int ldc,
    int M, int N, int K, int do_relu, int half_n, int aoff)
{
  __shared__ char smem[2 * BM * (BKK * 2)];  // As 16KB + Bs 16KB
  char* As = smem;
  char* Bs = smem + BM * BKK * 2;

  const int tid  = threadIdx.x;
  const int wid  = tid >> 6;
  const int lane = tid & 63;
  const int bn = blockIdx.x * BN;
  const int bm = blockIdx.y * BM;
  const int wm = ((wid >> 1) & 1) * 64;
  const int wn = (wid & 1) * 64;

  const int a0 = (half_n && bn >= half_n) ? aoff : 0;

  // staging: each wave stages 4 units of A and 4 of B (1KB each: 8 rows x 128B)
  const int srow = lane >> 3;              // row within unit
  const int sk8  = (lane & 7) ^ srow;      // pre-swizzled source chunk
  const u16* gA = A  + (size_t)(bm + 32*wid + srow) * lda + a0 + 8*sk8;
  const u16* gB = Wt + (size_t)(bn + 32*wid + srow) * K  + 8*sk8;

  const int frow = lane & 15;
  const int fk8  = lane >> 4;              // 0..3

  f32x4 acc[4][4] = {};

  for (int k0 = 0; k0 < K; k0 += BKK) {
#pragma unroll
    for (int i = 0; i < 4; ++i) {
      gload_lds16(gA + (size_t)i * 8 * lda, As + (4*wid + i) * 1024);
      gload_lds16(gB + (size_t)i * 8 * K,   Bs + (4*wid + i) * 1024);
    }
    gA += BKK; gB += BKK;
    asm volatile("s_waitcnt vmcnt(0)" ::: "memory");
    __syncthreads();

#pragma unroll
    for (int kh = 0; kh < 2; ++kh) {
      bf16x8 a[4], b[4];
#pragma unroll
      for (int m = 0; m < 4; ++m) {
        const int row  = wm + m*16 + frow;
        const int slot = (kh*4 + fk8) ^ (row & 7);
        a[m] = *(const bf16x8*)(As + row*128 + slot*16);
      }
#pragma unroll
      for (int n = 0; n < 4; ++n) {
        const int row  = wn + n*16 + frow;
        const int slot = (kh*4 + fk8) ^ (row & 7);
        b[n] = *(const bf16x8*)(Bs + row*128 + slot*16);
      }
#pragma unroll
      for (int m = 0; m < 4; ++m)
#pragma unroll
        for (int n = 0; n < 4; ++n)
          acc[m][n] = __builtin_amdgcn_mfma_f32_16x16x32_bf16(
              a[m], b[n], acc[m][n], 0, 0, 0);
    }
    __syncthreads();
  }

  // epilogue: C/D layout col = lane&15, row = (lane>>4)*4 + r
#pragma unroll
  for (int n = 0; n < 4; ++n) {
    const int col = bn + wn + n*16 + frow;
    const float bv = bias ? bias[col] : 0.f;
#pragma unroll
    for (int m = 0; m < 4; ++m) {
#pragma unroll
      for (int r = 0; r < 4; ++r) {
        const int row = bm + wm + m*16 + fk8*4 + r;
        float v = acc[m][n][r] + bv;
        if (do_relu) v = fmaxf(v, 0.f);
        C[(size_t)row * ldc + col] = f2bf(v);
      }
    }
  }
}

// ---------------------------------------------------------------------------
// per-entity linear terms from bf16 Hcat [4096][768] (cols 0..383=h, 384..=t)
// ---------------------------------------------------------------------------
__global__ __launch_bounds__(128) void lin_parts_kernel(
    const u16* __restrict__ Hcat, const float* __restrict__ W_lin,
    float* __restrict__ linHT)
{
  int be   = blockIdx.x;
  int wid  = threadIdx.x >> 6;   // 0: head part, 1: tail part
  int lane = threadIdx.x & 63;
  const u16* src = Hcat + (size_t)be * (2*HH_) + wid * HH_;
  const float* wl0 = W_lin + (wid ? HH_ : 0);
  const float* wl1 = W_lin + 2*HH_ + (wid ? HH_ : 0);
  float s0 = 0.f, s1 = 0.f;
#pragma unroll
  for (int t = 0; t < HH_/64; ++t) {
    int i = lane + t*64;
    float v = bf2f(src[i]);
    s0 += v * wl0[i];
    s1 += v * wl1[i];
  }
#pragma unroll
  for (int off = 32; off; off >>= 1) {
    s0 += __shfl_down(s0, off);
    s1 += __shfl_down(s1, off);
  }
  if (lane == 0) {
    linHT[be*4 + wid*2 + 0] = s0;
    linHT[be*4 + wid*2 + 1] = s1;
  }
}

__global__ void zero_out_kernel(float* __restrict__ out)
{
  if (threadIdx.x == 0) out[0] = 0.f;
}

// ---------------------------------------------------------------------------
// per-relation logits + CE; one wave per relation (grid-strided)
// ---------------------------------------------------------------------------
__global__ __launch_bounds__(256) void relation_loss_kernel(
    const int* __restrict__ rel_head, const int* __restrict__ rel_tail,
    const int* __restrict__ rel_label,
    const u16* __restrict__ Hcat, const u16* __restrict__ U,
    const float* __restrict__ linHT, const float* __restrict__ b_lin,
    float* __restrict__ out)
{
  const int NWAVE = gridDim.x * 4;
  int wave = blockIdx.x * 4 + (threadIdx.x >> 6);
  int lane = threadIdx.x & 63;
  float bl0 = b_lin[0], bl1 = b_lin[1];
  float acc = 0.f;

  for (int rel = wave; rel < B_*R_; rel += NWAVE) {
    int b  = rel >> 10;
    int rh = rel_head[rel];
    int rt = rel_tail[rel];
    int lab = rel_label[rel];
    const u16* h = Hcat + (size_t)(b*E_ + rh) * (2*HH_);  // head half
    const u16* u = U    + (size_t)(b*E_ + rt) * (2*HH_);
    float s0 = 0.f, s1 = 0.f;
#pragma unroll
    for (int t = 0; t < HH_/64; ++t) {
      int i = lane + t*64;
      float hv = bf2f(h[i]);
      s0 += hv * bf2f(u[i]);
      s1 += hv * bf2f(u[HH_ + i]);
    }
#pragma unroll
    for (int off = 32; off; off >>= 1) {
      s0 += __shfl_down(s0, off);
      s1 += __shfl_down(s1, off);
    }
    if (lane == 0) {
      int ih = (b*E_ + rh) * 4, it = (b*E_ + rt) * 4;
      float l0 = s0 + linHT[ih + 0] + linHT[it + 2] + bl0;
      float l1 = s1 + linHT[ih + 1] + linHT[it + 3] + bl1;
      float m = fmaxf(l0, l1);
      float lse = m + logf(expf(l0 - m) + expf(l1 - m));
      acc += lse - (lab == 0 ? l0 : l1);
    }
  }

  __shared__ float red[4];
  if (lane == 0) red[threadIdx.x >> 6] = acc;
  __syncthreads();
  if (threadIdx.x == 0)
    atomicAdd(out, (red[0] + red[1] + red[2] + red[3]) * (1.0f / R_));
}

// ---------------------------------------------------------------------------
extern "C" void kernel_launch(void* const* d_in, const int* in_sizes, int n_in,
                              void* d_out, int out_size, void* d_ws, size_t ws_size,
                              hipStream_t stream)
{
  const float* hs        = (const float*)d_in[0];
  const int*   rel_head  = (const int*)  d_in[1];
  const int*   rel_tail  = (const int*)  d_in[2];
  const int*   rel_label = (const int*)  d_in[3];
  const int*   ent_start = (const int*)  d_in[4];
  /* d_in[5] entities_end: unused by reference */
  const int*   ent_label = (const int*)  d_in[6];
  const float* emb   = (const float*)d_in[7];
  const float* Wh1   = (const float*)d_in[8];
  const float* bh1   = (const float*)d_in[9];
  const float* Wh2   = (const float*)d_in[10];
  const float* bh2   = (const float*)d_in[11];
  const float* Wt1   = (const float*)d_in[12];
  const float* bt1   = (const float*)d_in[13];
  const float* Wt2   = (const float*)d_in[14];
  const float* bt2   = (const float*)d_in[15];
  const float* W_bil = (const float*)d_in[16];
  const float* W_lin = (const float*)d_in[17];
  const float* b_lin = (const float*)d_in[18];
  float* out = (float*)d_out;

  // workspace layout (u16 elements unless noted)
  u16* X    = (u16*)d_ws;                 // 4096*1536
  u16* H1   = X    + (size_t)BE_ * K1_;   // 4096*1536
  u16* Hcat = H1   + (size_t)BE_ * K1_;   // 4096*768
  u16* U    = Hcat + (size_t)BE_ * H_;    // 4096*768
  u16* W1c  = U    + (size_t)BE_ * H_;    // 1536*1536
  u16* W2c  = W1c  + (size_t)K1_ * K1_;   // 768*768
  u16* Wb   = W2c  + (size_t)H_ * H_;     // 768*384
  float* bcat1 = (float*)(Wb + (size_t)H_ * HH_);  // 1536 f32
  float* b2cat = bcat1 + K1_;                      // 768 f32
  float* linHT = b2cat + H_;                       // 4096*4 f32

  // 1) weight conversion + bias concat
  prep_weights<<<dim3(3171), dim3(256), 0, stream>>>(
      Wh1, Wt1, Wh2, Wt2, W_bil, bh1, bt1, bh2, bt2,
      W1c, W2c, Wb, bcat1, b2cat);

  // 2) gather entity inputs (bf16)
  build_x_kernel<<<dim3(BE_), dim3(192), 0, stream>>>(
      hs, ent_start, ent_label, emb, X);

  // 3) layer-1 fused GEMM: H1 = relu(X @ [Wh1;Wt1]^T + bcat1)   [4096,1536]
  gemm_bf16<<<dim3(K1_/BN, BE_/BM), dim3(256), 0, stream>>>(
      X, K1_, W1c, bcat1, H1, K1_, BE_, K1_, K1_, 1, 0, 0);

  // 4) layer-2 fused GEMM: Hcat = relu([H1h@Wh2^T ; H1t@Wt2^T] + b2cat) [4096,768]
  gemm_bf16<<<dim3(H_/BN, BE_/BM), dim3(256), 0, stream>>>(
      H1, K1_, W2c, b2cat, Hcat, H_, BE_, H_, H_, 1, HH_, H_);

  // 5) bilinear hoist: U = Ht @ Wbil^T   [4096,768], K=384
  gemm_bf16<<<dim3(H_/BN, BE_/BM), dim3(256), 0, stream>>>(
      Hcat + HH_, H_, Wb, (const float*)nullptr, U, H_, BE_, H_, HH_, 0, 0, 0);

  // 6) per-entity linear terms
  lin_parts_kernel<<<dim3(BE_), dim3(128), 0, stream>>>(Hcat, W_lin, linHT);

  // 7) loss
  zero_out_kernel<<<dim3(1), dim3(64), 0, stream>>>(out);
  relation_loss_kernel<<<dim3(512), dim3(256), 0, stream>>>(
      rel_head, rel_tail, rel_label, Hcat, U, linHT, b_lin, out);
}

// Round 3
// 93.020 us; speedup vs baseline: 5.0793x; 1.1552x over previous
//
#include <hip/hip_runtime.h>
#include <math.h>

typedef unsigned short u16;
typedef __bf16 bf16x8 __attribute__((ext_vector_type(8)));
typedef float f32x4 __attribute__((ext_vector_type(4)));

#define B_ 32
#define W_ 512
#define H_ 768
#define HH_ 384
#define E_ 128
#define R_ 1024
#define BE_ (B_*E_)     /* 4096 */
#define K1_ (2*H_)      /* 1536 */

__device__ __forceinline__ u16 f2bf(float f) {
  unsigned u = __float_as_uint(f);
  u = (u + 0x7fffu + ((u >> 16) & 1u)) >> 16;   // RNE
  return (u16)u;
}
__device__ __forceinline__ float bf2f(u16 u) {
  return __uint_as_float(((unsigned)u) << 16);
}

__device__ __forceinline__ void gload_lds16(const void* g, void* l) {
  __builtin_amdgcn_global_load_lds(
      (__attribute__((address_space(1))) void*)(g),
      (__attribute__((address_space(3))) void*)(l), 16, 0, 0);
}

// ---------------------------------------------------------------------------
// Fused prep: (A) weight->bf16 conversion, (B) P table  P[l,n]=emb[l].W1[n,768:]+b1[n],
// (C) entity token gather to bf16. Partitioned by blockIdx.
// ---------------------------------------------------------------------------
#define NBLK_W 2017   /* 516288 float4 units / 256 */
#define NBLK_P 1152   /* 4608 waves (3*1536 dots), 4 waves/block */
#define NBLK_X 4096   /* one block per entity */

__global__ __launch_bounds__(256) void prep_all(
    const float* __restrict__ Wh1, const float* __restrict__ Wt1,
    const float* __restrict__ Wh2, const float* __restrict__ Wt2,
    const float* __restrict__ Wbil,
    const float* __restrict__ bh1, const float* __restrict__ bt1,
    const float* __restrict__ bh2, const float* __restrict__ bt2,
    const float* __restrict__ emb,
    const float* __restrict__ hs, const int* __restrict__ ent_start,
    u16* __restrict__ W1c, u16* __restrict__ W2c, u16* __restrict__ Wb,
    float* __restrict__ b2cat, float* __restrict__ P, u16* __restrict__ X)
{
  const int blk = blockIdx.x;
  const int tid = threadIdx.x;

  if (blk < NBLK_W) {
    // ---- weight conversion (float4 units) ----
    const int i = blk * 256 + tid;
    const int SW1 = 294912;              // W1c: 1536 rows x 768 cols /4
    const int SW2 = SW1 + 147456;        // W2c: 768x768 /4
    const int SWB = SW2 + 73728;         // Wb:  768x384 /4
    const int SB2 = SWB + 192;           // b2cat: 768 /4
    if (i < SW1) {
      int row = i / 192, c = i % 192;    // c: float4 unit within 768 cols
      const float4* src = (const float4*)((row < 768)
          ? (Wh1 + (size_t)row * K1_) : (Wt1 + (size_t)(row - 768) * K1_));
      float4 v = src[c];
      ushort4 o; o.x = f2bf(v.x); o.y = f2bf(v.y); o.z = f2bf(v.z); o.w = f2bf(v.w);
      ((ushort4*)W1c)[i] = o;
    } else if (i < SW2) {
      int j = i - SW1;
      float4 v = (j < 73728) ? ((const float4*)Wh2)[j]
                             : ((const float4*)Wt2)[j - 73728];
      ushort4 o; o.x = f2bf(v.x); o.y = f2bf(v.y); o.z = f2bf(v.z); o.w = f2bf(v.w);
      ((ushort4*)W2c)[j] = o;
    } else if (i < SWB) {
      int j = i - SW2;
      float4 v = ((const float4*)Wbil)[j];
      ushort4 o; o.x = f2bf(v.x); o.y = f2bf(v.y); o.z = f2bf(v.z); o.w = f2bf(v.w);
      ((ushort4*)Wb)[j] = o;
    } else if (i < SB2) {
      int j = i - SWB;
      ((float4*)b2cat)[j] = (j < 96) ? ((const float4*)bh2)[j]
                                     : ((const float4*)bt2)[j - 96];
    }
  } else if (blk < NBLK_W + NBLK_P) {
    // ---- P table: one wave per (l,n) dot over 768 (fp32) ----
    const int w = (blk - NBLK_W) * 4 + (tid >> 6);
    const int lane = tid & 63;
    const int l = w / K1_;
    const int n = w - l * K1_;
    const float* wrow = (n < 768) ? (Wh1 + (size_t)n * K1_ + 768)
                                  : (Wt1 + (size_t)(n - 768) * K1_ + 768);
    const float  bb   = (n < 768) ? bh1[n] : bt1[n - 768];
    const float* ev = emb + (size_t)l * H_;
    float s = 0.f;
#pragma unroll
    for (int t = 0; t < 12; ++t) {
      int d = lane + 64 * t;
      s += ev[d] * wrow[d];
    }
#pragma unroll
    for (int off = 32; off; off >>= 1) s += __shfl_down(s, off);
    if (lane == 0) P[(size_t)l * K1_ + n] = s + bb;
  } else {
    // ---- gather entity tokens to bf16: X[be,:] = hs[b, start, :] ----
    const int be = blk - (NBLK_W + NBLK_P);
    if (tid < 192) {
      int b = be >> 7;
      int start = ent_start[be];
      const float4* s0 = (const float4*)(hs + ((size_t)b * W_ + start) * H_);
      float4 v = s0[tid];
      ushort4 o; o.x = f2bf(v.x); o.y = f2bf(v.y); o.z = f2bf(v.z); o.w = f2bf(v.w);
      ((ushort4*)(X + (size_t)be * H_))[tid] = o;
    }
  }
}

// ---------------------------------------------------------------------------
// bf16 MFMA GEMM: C[M,N] = act(A[M,K(lda)] @ Wt[N,K]^T + bias [+ P[label[row]]])
// 128x128 tile, BK=64, 4 waves (2x2), 64x64/wave of 16x16x32 fragments.
// global_load_lds(16B), linear LDS + pre-swizzled source (XOR row&7).
// ---------------------------------------------------------------------------
#define BM 128
#define BN 128
#define BKK 64

__global__ __launch_bounds__(256, 2) void gemm_bf16(
    const u16* __restrict__ A, int lda,
    const u16* __restrict__ Wt,              // [N][K] row-major
    const float* __restrict__ bias,
    u16* __restrict__ C, int ldc,
    int M, int N, int K, int do_relu, int half_n, int aoff,
    const float* __restrict__ rowBias,       // P [3][ldP] or null
    const int* __restrict__ rowLabel, int ldP)
{
  __shared__ char smem[2 * BM * (BKK * 2)];  // As 16KB + Bs 16KB
  char* As = smem;
  char* Bs = smem + BM * BKK * 2;

  const int tid  = threadIdx.x;
  const int wid  = tid >> 6;
  const int lane = tid & 63;
  const int bn = blockIdx.x * BN;
  const int bm = blockIdx.y * BM;
  const int wm = ((wid >> 1) & 1) * 64;
  const int wn = (wid & 1) * 64;

  const int a0 = (half_n && bn >= half_n) ? aoff : 0;

  const int srow = lane >> 3;
  const int sk8  = (lane & 7) ^ srow;
  const u16* gA = A  + (size_t)(bm + 32*wid + srow) * lda + a0 + 8*sk8;
  const u16* gB = Wt + (size_t)(bn + 32*wid + srow) * K  + 8*sk8;

  const int frow = lane & 15;
  const int fk8  = lane >> 4;

  f32x4 acc[4][4] = {};

  for (int k0 = 0; k0 < K; k0 += BKK) {
#pragma unroll
    for (int i = 0; i < 4; ++i) {
      gload_lds16(gA + (size_t)i * 8 * lda, As + (4*wid + i) * 1024);
      gload_lds16(gB + (size_t)i * 8 * K,   Bs + (4*wid + i) * 1024);
    }
    gA += BKK; gB += BKK;
    asm volatile("s_waitcnt vmcnt(0)" ::: "memory");
    __syncthreads();

#pragma unroll
    for (int kh = 0; kh < 2; ++kh) {
      bf16x8 a[4], b[4];
#pragma unroll
      for (int m = 0; m < 4; ++m) {
        const int row  = wm + m*16 + frow;
        const int slot = (kh*4 + fk8) ^ (row & 7);
        a[m] = *(const bf16x8*)(As + row*128 + slot*16);
      }
#pragma unroll
      for (int n = 0; n < 4; ++n) {
        const int row  = wn + n*16 + frow;
        const int slot = (kh*4 + fk8) ^ (row & 7);
        b[n] = *(const bf16x8*)(Bs + row*128 + slot*16);
      }
#pragma unroll
      for (int m = 0; m < 4; ++m)
#pragma unroll
        for (int n = 0; n < 4; ++n)
          acc[m][n] = __builtin_amdgcn_mfma_f32_16x16x32_bf16(
              a[m], b[n], acc[m][n], 0, 0, 0);
    }
    __syncthreads();
  }

  // hoist per-row labels (16 rows/thread)
  int lbl[4][4];
  if (rowLabel) {
#pragma unroll
    for (int m = 0; m < 4; ++m)
#pragma unroll
      for (int r = 0; r < 4; ++r)
        lbl[m][r] = rowLabel[bm + wm + m*16 + fk8*4 + r];
  }

  // epilogue: C/D layout col = lane&15, row = (lane>>4)*4 + r
#pragma unroll
  for (int n = 0; n < 4; ++n) {
    const int col = bn + wn + n*16 + frow;
    const float bv = bias ? bias[col] : 0.f;
    float p0 = 0.f, p1 = 0.f, p2 = 0.f;
    if (rowLabel) {
      p0 = rowBias[col];
      p1 = rowBias[ldP + col];
      p2 = rowBias[2*ldP + col];
    }
#pragma unroll
    for (int m = 0; m < 4; ++m) {
#pragma unroll
      for (int r = 0; r < 4; ++r) {
        const int row = bm + wm + m*16 + fk8*4 + r;
        float v = acc[m][n][r] + bv;
        if (rowLabel) {
          int l = lbl[m][r];
          v += (l == 0) ? p0 : ((l == 1) ? p1 : p2);
        }
        if (do_relu) v = fmaxf(v, 0.f);
        C[(size_t)row * ldc + col] = f2bf(v);
      }
    }
  }
}

// ---------------------------------------------------------------------------
// per-entity linear terms from bf16 Hcat [4096][768]; block 0 zeroes out[0]
// ---------------------------------------------------------------------------
__global__ __launch_bounds__(128) void lin_parts_kernel(
    const u16* __restrict__ Hcat, const float* __restrict__ W_lin,
    float* __restrict__ linHT, float* __restrict__ out)
{
  if (blockIdx.x == 0 && threadIdx.x == 0) out[0] = 0.f;
  int be   = blockIdx.x;
  int wid  = threadIdx.x >> 6;   // 0: head, 1: tail
  int lane = threadIdx.x & 63;
  const u16* src = Hcat + (size_t)be * (2*HH_) + wid * HH_;
  const float* wl0 = W_lin + (wid ? HH_ : 0);
  const float* wl1 = W_lin + 2*HH_ + (wid ? HH_ : 0);
  float s0 = 0.f, s1 = 0.f;
#pragma unroll
  for (int t = 0; t < HH_/64; ++t) {
    int i = lane + t*64;
    float v = bf2f(src[i]);
    s0 += v * wl0[i];
    s1 += v * wl1[i];
  }
#pragma unroll
  for (int off = 32; off; off >>= 1) {
    s0 += __shfl_down(s0, off);
    s1 += __shfl_down(s1, off);
  }
  if (lane == 0) {
    linHT[be*4 + wid*2 + 0] = s0;
    linHT[be*4 + wid*2 + 1] = s1;
  }
}

// ---------------------------------------------------------------------------
// per-relation logits + CE; one wave per relation (grid-strided)
// ---------------------------------------------------------------------------
__global__ __launch_bounds__(256) void relation_loss_kernel(
    const int* __restrict__ rel_head, const int* __restrict__ rel_tail,
    const int* __restrict__ rel_label,
    const u16* __restrict__ Hcat, const u16* __restrict__ U,
    const float* __restrict__ linHT, const float* __restrict__ b_lin,
    float* __restrict__ out)
{
  const int NWAVE = gridDim.x * 4;
  int wave = blockIdx.x * 4 + (threadIdx.x >> 6);
  int lane = threadIdx.x & 63;
  float bl0 = b_lin[0], bl1 = b_lin[1];
  float acc = 0.f;

  for (int rel = wave; rel < B_*R_; rel += NWAVE) {
    int b  = rel >> 10;
    int rh = rel_head[rel];
    int rt = rel_tail[rel];
    int lab = rel_label[rel];
    const u16* h = Hcat + (size_t)(b*E_ + rh) * (2*HH_);  // head half
    const u16* u = U    + (size_t)(b*E_ + rt) * (2*HH_);
    float s0 = 0.f, s1 = 0.f;
#pragma unroll
    for (int t = 0; t < HH_/64; ++t) {
      int i = lane + t*64;
      float hv = bf2f(h[i]);
      s0 += hv * bf2f(u[i]);
      s1 += hv * bf2f(u[HH_ + i]);
    }
#pragma unroll
    for (int off = 32; off; off >>= 1) {
      s0 += __shfl_down(s0, off);
      s1 += __shfl_down(s1, off);
    }
    if (lane == 0) {
      int ih = (b*E_ + rh) * 4, it = (b*E_ + rt) * 4;
      float l0 = s0 + linHT[ih + 0] + linHT[it + 2] + bl0;
      float l1 = s1 + linHT[ih + 1] + linHT[it + 3] + bl1;
      float m = fmaxf(l0, l1);
      float lse = m + logf(expf(l0 - m) + expf(l1 - m));
      acc += lse - (lab == 0 ? l0 : l1);
    }
  }

  __shared__ float red[4];
  if (lane == 0) red[threadIdx.x >> 6] = acc;
  __syncthreads();
  if (threadIdx.x == 0)
    atomicAdd(out, (red[0] + red[1] + red[2] + red[3]) * (1.0f / R_));
}

// ---------------------------------------------------------------------------
extern "C" void kernel_launch(void* const* d_in, const int* in_sizes, int n_in,
                              void* d_out, int out_size, void* d_ws, size_t ws_size,
                              hipStream_t stream)
{
  const float* hs        = (const float*)d_in[0];
  const int*   rel_head  = (const int*)  d_in[1];
  const int*   rel_tail  = (const int*)  d_in[2];
  const int*   rel_label = (const int*)  d_in[3];
  const int*   ent_start = (const int*)  d_in[4];
  /* d_in[5] entities_end: unused by reference */
  const int*   ent_label = (const int*)  d_in[6];
  const float* emb   = (const float*)d_in[7];
  const float* Wh1   = (const float*)d_in[8];
  const float* bh1   = (const float*)d_in[9];
  const float* Wh2   = (const float*)d_in[10];
  const float* bh2   = (const float*)d_in[11];
  const float* Wt1   = (const float*)d_in[12];
  const float* bt1   = (const float*)d_in[13];
  const float* Wt2   = (const float*)d_in[14];
  const float* bt2   = (const float*)d_in[15];
  const float* W_bil = (const float*)d_in[16];
  const float* W_lin = (const float*)d_in[17];
  const float* b_lin = (const float*)d_in[18];
  float* out = (float*)d_out;

  // workspace layout
  u16* X    = (u16*)d_ws;                 // 4096*768
  u16* H1   = X    + (size_t)BE_ * H_;    // 4096*1536
  u16* Hcat = H1   + (size_t)BE_ * K1_;   // 4096*768
  u16* U    = Hcat + (size_t)BE_ * H_;    // 4096*768
  u16* W1c  = U    + (size_t)BE_ * H_;    // 1536*768
  u16* W2c  = W1c  + (size_t)K1_ * H_;    // 768*768
  u16* Wb   = W2c  + (size_t)H_ * H_;     // 768*384
  float* b2cat = (float*)(Wb + (size_t)H_ * HH_);  // 768 f32
  float* P     = b2cat + H_;                       // 3*1536 f32
  float* linHT = P + 3*K1_;                        // 4096*4 f32

  // 1) fused prep: weights->bf16, P table, token gather
  prep_all<<<dim3(NBLK_W + NBLK_P + NBLK_X), dim3(256), 0, stream>>>(
      Wh1, Wt1, Wh2, Wt2, W_bil, bh1, bt1, bh2, bt2, emb,
      hs, ent_start, W1c, W2c, Wb, b2cat, P, X);

  // 2) layer-1 GEMM (K halved via P): H1 = relu(X @ W1c^T + P[label]) [4096,1536]
  gemm_bf16<<<dim3(K1_/BN, BE_/BM), dim3(256), 0, stream>>>(
      X, H_, W1c, (const float*)nullptr, H1, K1_, BE_, K1_, H_, 1, 0, 0,
      P, ent_label, K1_);

  // 3) layer-2 fused GEMM: Hcat = relu([H1h@Wh2^T ; H1t@Wt2^T] + b2cat) [4096,768]
  gemm_bf16<<<dim3(H_/BN, BE_/BM), dim3(256), 0, stream>>>(
      H1, K1_, W2c, b2cat, Hcat, H_, BE_, H_, H_, 1, HH_, H_,
      (const float*)nullptr, (const int*)nullptr, 0);

  // 4) bilinear hoist: U = Ht @ Wbil^T   [4096,768], K=384
  gemm_bf16<<<dim3(H_/BN, BE_/BM), dim3(256), 0, stream>>>(
      Hcat + HH_, H_, Wb, (const float*)nullptr, U, H_, BE_, H_, HH_, 0, 0, 0,
      (const float*)nullptr, (const int*)nullptr, 0);

  // 5) per-entity linear terms (+ zero out)
  lin_parts_kernel<<<dim3(BE_), dim3(128), 0, stream>>>(Hcat, W_lin, linHT, out);

  // 6) loss
  relation_loss_kernel<<<dim3(512), dim3(256), 0, stream>>>(
      rel_head, rel_tail, rel_label, Hcat, U, linHT, b_lin, out);
}

// Round 4
// 75.731 us; speedup vs baseline: 6.2389x; 1.2283x over previous
//
#include <hip/hip_runtime.h>
#include <math.h>

typedef unsigned short u16;
typedef __bf16 bf16x8 __attribute__((ext_vector_type(8)));
typedef float f32x4 __attribute__((ext_vector_type(4)));

#define B_ 32
#define W_ 512
#define H_ 768
#define HH_ 384
#define E_ 128
#define R_ 1024
#define BE_ (B_*E_)     /* 4096 */
#define K1_ (2*H_)      /* 1536 */

__device__ __forceinline__ u16 f2bf(float f) {
  unsigned u = __float_as_uint(f);
  u = (u + 0x7fffu + ((u >> 16) & 1u)) >> 16;   // RNE
  return (u16)u;
}
__device__ __forceinline__ float bf2f(u16 u) {
  return __uint_as_float(((unsigned)u) << 16);
}

__device__ __forceinline__ void gload_lds16(const void* g, void* l) {
  __builtin_amdgcn_global_load_lds(
      (__attribute__((address_space(1))) void*)(g),
      (__attribute__((address_space(3))) void*)(l), 16, 0, 0);
}

// bijective XCD-chunked block swizzle (m204): each XCD gets a contiguous
// chunk of linear block ids -> A-panel reuse stays in its private L2.
__device__ __forceinline__ void xcd_swizzle(int& bx, int& by) {
  const int nwg = gridDim.x * gridDim.y;
  int orig = blockIdx.y * gridDim.x + blockIdx.x;
  int q = nwg >> 3, r = nwg & 7;
  int xcd = orig & 7, idx = orig >> 3;
  int wgid = (xcd < r ? xcd * (q + 1) : r * (q + 1) + (xcd - r) * q) + idx;
  bx = wgid % gridDim.x;
  by = wgid / gridDim.x;
}

// ---------------------------------------------------------------------------
// Fused prep: (A) weight->bf16, (B) P table P[l,n]=emb[l].W1[n,768:]+b1[n],
// (C) entity token gather to bf16.
// ---------------------------------------------------------------------------
#define NBLK_W 2017
#define NBLK_P 1152
#define NBLK_X 4096

__global__ __launch_bounds__(256) void prep_all(
    const float* __restrict__ Wh1, const float* __restrict__ Wt1,
    const float* __restrict__ Wh2, const float* __restrict__ Wt2,
    const float* __restrict__ Wbil,
    const float* __restrict__ bh1, const float* __restrict__ bt1,
    const float* __restrict__ bh2, const float* __restrict__ bt2,
    const float* __restrict__ emb,
    const float* __restrict__ hs, const int* __restrict__ ent_start,
    u16* __restrict__ W1c, u16* __restrict__ W2c, u16* __restrict__ Wb,
    float* __restrict__ b2cat, float* __restrict__ P, u16* __restrict__ X)
{
  const int blk = blockIdx.x;
  const int tid = threadIdx.x;

  if (blk < NBLK_W) {
    const int i = blk * 256 + tid;
    const int SW1 = 294912;              // W1c: 1536 rows x 768 cols /4
    const int SW2 = SW1 + 147456;        // W2c: 768x768 /4
    const int SWB = SW2 + 73728;         // Wb:  768x384 /4
    const int SB2 = SWB + 192;           // b2cat: 768 /4
    if (i < SW1) {
      int row = i / 192, c = i % 192;
      const float4* src = (const float4*)((row < 768)
          ? (Wh1 + (size_t)row * K1_) : (Wt1 + (size_t)(row - 768) * K1_));
      float4 v = src[c];
      ushort4 o; o.x = f2bf(v.x); o.y = f2bf(v.y); o.z = f2bf(v.z); o.w = f2bf(v.w);
      ((ushort4*)W1c)[i] = o;
    } else if (i < SW2) {
      int j = i - SW1;
      float4 v = (j < 73728) ? ((const float4*)Wh2)[j]
                             : ((const float4*)Wt2)[j - 73728];
      ushort4 o; o.x = f2bf(v.x); o.y = f2bf(v.y); o.z = f2bf(v.z); o.w = f2bf(v.w);
      ((ushort4*)W2c)[j] = o;
    } else if (i < SWB) {
      int j = i - SW2;
      float4 v = ((const float4*)Wbil)[j];
      ushort4 o; o.x = f2bf(v.x); o.y = f2bf(v.y); o.z = f2bf(v.z); o.w = f2bf(v.w);
      ((ushort4*)Wb)[j] = o;
    } else if (i < SB2) {
      int j = i - SWB;
      ((float4*)b2cat)[j] = (j < 96) ? ((const float4*)bh2)[j]
                                     : ((const float4*)bt2)[j - 96];
    }
  } else if (blk < NBLK_W + NBLK_P) {
    const int w = (blk - NBLK_W) * 4 + (tid >> 6);
    const int lane = tid & 63;
    const int l = w / K1_;
    const int n = w - l * K1_;
    const float* wrow = (n < 768) ? (Wh1 + (size_t)n * K1_ + 768)
                                  : (Wt1 + (size_t)(n - 768) * K1_ + 768);
    const float  bb   = (n < 768) ? bh1[n] : bt1[n - 768];
    const float* ev = emb + (size_t)l * H_;
    float s = 0.f;
#pragma unroll
    for (int t = 0; t < 12; ++t) {
      int d = lane + 64 * t;
      s += ev[d] * wrow[d];
    }
#pragma unroll
    for (int off = 32; off; off >>= 1) s += __shfl_down(s, off);
    if (lane == 0) P[(size_t)l * K1_ + n] = s + bb;
  } else {
    const int be = blk - (NBLK_W + NBLK_P);
    if (tid < 192) {
      int b = be >> 7;
      int start = ent_start[be];
      const float4* s0 = (const float4*)(hs + ((size_t)b * W_ + start) * H_);
      float4 v = s0[tid];
      ushort4 o; o.x = f2bf(v.x); o.y = f2bf(v.y); o.z = f2bf(v.z); o.w = f2bf(v.w);
      ((ushort4*)(X + (size_t)be * H_))[tid] = o;
    }
  }
}

// ---------------------------------------------------------------------------
// bf16 MFMA GEMM: C[M,N] = act(A[M,K(lda)] @ Wt[N,K]^T + bias [+ P[label[row]]])
// 128x128 tile, BK=64, 4 waves (2x2). global_load_lds(16B), linear LDS +
// pre-swizzled source (XOR row&7). XCD-chunked block swizzle.
// ---------------------------------------------------------------------------
#define BM 128
#define BN 128
#define BKK 64

__global__ __launch_bounds__(256, 2) void gemm_bf16(
    const u16* __restrict__ A, int lda,
    const u16* __restrict__ Wt,              // [N][K] row-major
    const float* __restrict__ bias,
    u16* __restrict__ C, int ldc,
    int M, int N, int K, int do_relu, int half_n, int aoff,
    const float* __restrict__ rowBias,       // P [3][ldP] or null
    const int* __restrict__ rowLabel, int ldP)
{
  __shared__ char smem[2 * BM * (BKK * 2)];
  char* As = smem;
  char* Bs = smem + BM * BKK * 2;

  int bx, by;
  xcd_swizzle(bx, by);
  const int bn = bx * BN;
  const int bm = by * BM;

  const int tid  = threadIdx.x;
  const int wid  = tid >> 6;
  const int lane = tid & 63;
  const int wm = ((wid >> 1) & 1) * 64;
  const int wn = (wid & 1) * 64;

  const int a0 = (half_n && bn >= half_n) ? aoff : 0;

  const int srow = lane >> 3;
  const int sk8  = (lane & 7) ^ srow;
  const u16* gA = A  + (size_t)(bm + 32*wid + srow) * lda + a0 + 8*sk8;
  const u16* gB = Wt + (size_t)(bn + 32*wid + srow) * K  + 8*sk8;

  const int frow = lane & 15;
  const int fk8  = lane >> 4;

  f32x4 acc[4][4] = {};

  for (int k0 = 0; k0 < K; k0 += BKK) {
#pragma unroll
    for (int i = 0; i < 4; ++i) {
      gload_lds16(gA + (size_t)i * 8 * lda, As + (4*wid + i) * 1024);
      gload_lds16(gB + (size_t)i * 8 * K,   Bs + (4*wid + i) * 1024);
    }
    gA += BKK; gB += BKK;
    asm volatile("s_waitcnt vmcnt(0)" ::: "memory");
    __syncthreads();

#pragma unroll
    for (int kh = 0; kh < 2; ++kh) {
      bf16x8 a[4], b[4];
#pragma unroll
      for (int m = 0; m < 4; ++m) {
        const int row  = wm + m*16 + frow;
        const int slot = (kh*4 + fk8) ^ (row & 7);
        a[m] = *(const bf16x8*)(As + row*128 + slot*16);
      }
#pragma unroll
      for (int n = 0; n < 4; ++n) {
        const int row  = wn + n*16 + frow;
        const int slot = (kh*4 + fk8) ^ (row & 7);
        b[n] = *(const bf16x8*)(Bs + row*128 + slot*16);
      }
#pragma unroll
      for (int m = 0; m < 4; ++m)
#pragma unroll
        for (int n = 0; n < 4; ++n)
          acc[m][n] = __builtin_amdgcn_mfma_f32_16x16x32_bf16(
              a[m], b[n], acc[m][n], 0, 0, 0);
    }
    __syncthreads();
  }

  int lbl[4][4];
  if (rowLabel) {
#pragma unroll
    for (int m = 0; m < 4; ++m)
#pragma unroll
      for (int r = 0; r < 4; ++r)
        lbl[m][r] = rowLabel[bm + wm + m*16 + fk8*4 + r];
  }

#pragma unroll
  for (int n = 0; n < 4; ++n) {
    const int col = bn + wn + n*16 + frow;
    const float bv = bias ? bias[col] : 0.f;
    float p0 = 0.f, p1 = 0.f, p2 = 0.f;
    if (rowLabel) {
      p0 = rowBias[col];
      p1 = rowBias[ldP + col];
      p2 = rowBias[2*ldP + col];
    }
#pragma unroll
    for (int m = 0; m < 4; ++m) {
#pragma unroll
      for (int r = 0; r < 4; ++r) {
        const int row = bm + wm + m*16 + fk8*4 + r;
        float v = acc[m][n][r] + bv;
        if (rowLabel) {
          int l = lbl[m][r];
          v += (l == 0) ? p0 : ((l == 1) ? p1 : p2);
        }
        if (do_relu) v = fmaxf(v, 0.f);
        C[(size_t)row * ldc + col] = f2bf(v);
      }
    }
  }
}

// ---------------------------------------------------------------------------
// Batched score GEMM: per doc z,  S[z, e1, e2*2+o] =
//   Hh[z,e1,:384] . U[z,e2, o*384:o*384+384]  + linH[o][e1] + linT[o][e2] + b_lin[o]
// A = Hcat + z*128*768 (head cols, lda=768); B = U + z*128*768 viewed [256][384].
// Output f32. grid (2, 32).
// ---------------------------------------------------------------------------
__global__ __launch_bounds__(256, 2) void gemm_S(
    const u16* __restrict__ Hcat, const u16* __restrict__ U,
    const float* __restrict__ linHT, const float* __restrict__ b_lin,
    float* __restrict__ S)
{
  __shared__ char smem[2 * 128 * 128];
  char* As = smem;
  char* Bs = smem + 128 * 128;

  int bx, by;
  xcd_swizzle(bx, by);
  const int z  = by;
  const int bn = bx * 128;

  const int tid  = threadIdx.x;
  const int wid  = tid >> 6;
  const int lane = tid & 63;
  const int wm = ((wid >> 1) & 1) * 64;
  const int wn = (wid & 1) * 64;

  const int srow = lane >> 3;
  const int sk8  = (lane & 7) ^ srow;
  const u16* gA = Hcat + (size_t)z * 128 * 768 + (size_t)(32*wid + srow) * 768 + 8*sk8;
  const u16* gB = U    + (size_t)z * 128 * 768 + (size_t)(bn + 32*wid + srow) * 384 + 8*sk8;

  const int frow = lane & 15;
  const int fk8  = lane >> 4;

  f32x4 acc[4][4] = {};

  for (int k0 = 0; k0 < 384; k0 += BKK) {
#pragma unroll
    for (int i = 0; i < 4; ++i) {
      gload_lds16(gA + (size_t)i * 8 * 768, As + (4*wid + i) * 1024);
      gload_lds16(gB + (size_t)i * 8 * 384, Bs + (4*wid + i) * 1024);
    }
    gA += BKK; gB += BKK;
    asm volatile("s_waitcnt vmcnt(0)" ::: "memory");
    __syncthreads();

#pragma unroll
    for (int kh = 0; kh < 2; ++kh) {
      bf16x8 a[4], b[4];
#pragma unroll
      for (int m = 0; m < 4; ++m) {
        const int row  = wm + m*16 + frow;
        const int slot = (kh*4 + fk8) ^ (row & 7);
        a[m] = *(const bf16x8*)(As + row*128 + slot*16);
      }
#pragma unroll
      for (int n = 0; n < 4; ++n) {
        const int row  = wn + n*16 + frow;
        const int slot = (kh*4 + fk8) ^ (row & 7);
        b[n] = *(const bf16x8*)(Bs + row*128 + slot*16);
      }
#pragma unroll
      for (int m = 0; m < 4; ++m)
#pragma unroll
        for (int n = 0; n < 4; ++n)
          acc[m][n] = __builtin_amdgcn_mfma_f32_16x16x32_bf16(
              a[m], b[n], acc[m][n], 0, 0, 0);
    }
    __syncthreads();
  }

  // epilogue: n_out = bn+wn+n*16+frow; o = n_out&1 (fixed per thread), e2 = n_out>>1
  const int o = (bn + wn + frow) & 1;
  const float blv = b_lin[o];
  float linHrow[4][4];
#pragma unroll
  for (int m = 0; m < 4; ++m)
#pragma unroll
    for (int r = 0; r < 4; ++r)
      linHrow[m][r] = linHT[(size_t)(z*128 + wm + m*16 + fk8*4 + r) * 4 + o];

#pragma unroll
  for (int n = 0; n < 4; ++n) {
    const int n_out = bn + wn + n*16 + frow;
    const int e2 = n_out >> 1;
    const float lt = linHT[(size_t)(z*128 + e2) * 4 + 2 + o];
#pragma unroll
    for (int m = 0; m < 4; ++m) {
#pragma unroll
      for (int r = 0; r < 4; ++r) {
        const int row = wm + m*16 + fk8*4 + r;
        S[((size_t)(z*128 + row)) * 256 + n_out] =
            acc[m][n][r] + linHrow[m][r] + lt + blv;
      }
    }
  }
}

// ---------------------------------------------------------------------------
// per-entity linear terms from bf16 Hcat [4096][768]; block 0 zeroes out[0]
// ---------------------------------------------------------------------------
__global__ __launch_bounds__(128) void lin_parts_kernel(
    const u16* __restrict__ Hcat, const float* __restrict__ W_lin,
    float* __restrict__ linHT, float* __restrict__ out)
{
  if (blockIdx.x == 0 && threadIdx.x == 0) out[0] = 0.f;
  int be   = blockIdx.x;
  int wid  = threadIdx.x >> 6;   // 0: head, 1: tail
  int lane = threadIdx.x & 63;
  const u16* src = Hcat + (size_t)be * (2*HH_) + wid * HH_;
  const float* wl0 = W_lin + (wid ? HH_ : 0);
  const float* wl1 = W_lin + 2*HH_ + (wid ? HH_ : 0);
  float s0 = 0.f, s1 = 0.f;
#pragma unroll
  for (int t = 0; t < HH_/64; ++t) {
    int i = lane + t*64;
    float v = bf2f(src[i]);
    s0 += v * wl0[i];
    s1 += v * wl1[i];
  }
#pragma unroll
  for (int off = 32; off; off >>= 1) {
    s0 += __shfl_down(s0, off);
    s1 += __shfl_down(s1, off);
  }
  if (lane == 0) {
    linHT[be*4 + wid*2 + 0] = s0;
    linHT[be*4 + wid*2 + 1] = s1;
  }
}

// ---------------------------------------------------------------------------
// CE over precomputed logits S: one thread per relation (32768 = 128 blocks)
// ---------------------------------------------------------------------------
__global__ __launch_bounds__(256) void ce_kernel(
    const int* __restrict__ rel_head, const int* __restrict__ rel_tail,
    const int* __restrict__ rel_label, const float* __restrict__ S,
    float* __restrict__ out)
{
  const int i = blockIdx.x * 256 + threadIdx.x;
  const int b  = i >> 10;
  const int rh = rel_head[i];
  const int rt = rel_tail[i];
  const int lab = rel_label[i];
  const float2 lv = *(const float2*)(S + ((size_t)(b*E_ + rh)) * 256 + rt*2);
  const float l0 = lv.x, l1 = lv.y;
  const float m = fmaxf(l0, l1);
  const float lse = m + logf(expf(l0 - m) + expf(l1 - m));
  float nll = lse - (lab == 0 ? l0 : l1);

#pragma unroll
  for (int off = 32; off; off >>= 1) nll += __shfl_down(nll, off);
  __shared__ float red[4];
  if ((threadIdx.x & 63) == 0) red[threadIdx.x >> 6] = nll;
  __syncthreads();
  if (threadIdx.x == 0)
    atomicAdd(out, (red[0] + red[1] + red[2] + red[3]) * (1.0f / R_));
}

// ---------------------------------------------------------------------------
extern "C" void kernel_launch(void* const* d_in, const int* in_sizes, int n_in,
                              void* d_out, int out_size, void* d_ws, size_t ws_size,
                              hipStream_t stream)
{
  const float* hs        = (const float*)d_in[0];
  const int*   rel_head  = (const int*)  d_in[1];
  const int*   rel_tail  = (const int*)  d_in[2];
  const int*   rel_label = (const int*)  d_in[3];
  const int*   ent_start = (const int*)  d_in[4];
  const int*   ent_label = (const int*)  d_in[6];
  const float* emb   = (const float*)d_in[7];
  const float* Wh1   = (const float*)d_in[8];
  const float* bh1   = (const float*)d_in[9];
  const float* Wh2   = (const float*)d_in[10];
  const float* bh2   = (const float*)d_in[11];
  const float* Wt1   = (const float*)d_in[12];
  const float* bt1   = (const float*)d_in[13];
  const float* Wt2   = (const float*)d_in[14];
  const float* bt2   = (const float*)d_in[15];
  const float* W_bil = (const float*)d_in[16];
  const float* W_lin = (const float*)d_in[17];
  const float* b_lin = (const float*)d_in[18];
  float* out = (float*)d_out;

  // workspace layout
  u16* X    = (u16*)d_ws;                 // 4096*768
  u16* H1   = X    + (size_t)BE_ * H_;    // 4096*1536
  u16* Hcat = H1   + (size_t)BE_ * K1_;   // 4096*768
  u16* U    = Hcat + (size_t)BE_ * H_;    // 4096*768
  u16* W1c  = U    + (size_t)BE_ * H_;    // 1536*768
  u16* W2c  = W1c  + (size_t)K1_ * H_;    // 768*768
  u16* Wb   = W2c  + (size_t)H_ * H_;     // 768*384
  float* b2cat = (float*)(Wb + (size_t)H_ * HH_);  // 768
  float* P     = b2cat + H_;                       // 3*1536
  float* linHT = P + 3*K1_;                        // 4096*4
  float* S     = linHT + 4*BE_;                    // 4096*256

  // 1) fused prep
  prep_all<<<dim3(NBLK_W + NBLK_P + NBLK_X), dim3(256), 0, stream>>>(
      Wh1, Wt1, Wh2, Wt2, W_bil, bh1, bt1, bh2, bt2, emb,
      hs, ent_start, W1c, W2c, Wb, b2cat, P, X);

  // 2) layer-1 GEMM: H1 = relu(X @ W1c^T + P[label]) [4096,1536], K=768
  gemm_bf16<<<dim3(K1_/BN, BE_/BM), dim3(256), 0, stream>>>(
      X, H_, W1c, (const float*)nullptr, H1, K1_, BE_, K1_, H_, 1, 0, 0,
      P, ent_label, K1_);

  // 3) layer-2 fused GEMM: Hcat = relu([H1h@Wh2^T ; H1t@Wt2^T] + b2cat) [4096,768]
  gemm_bf16<<<dim3(H_/BN, BE_/BM), dim3(256), 0, stream>>>(
      H1, K1_, W2c, b2cat, Hcat, H_, BE_, H_, H_, 1, HH_, H_,
      (const float*)nullptr, (const int*)nullptr, 0);

  // 4) per-entity linear terms (+ zero out)
  lin_parts_kernel<<<dim3(BE_), dim3(128), 0, stream>>>(Hcat, W_lin, linHT, out);

  // 5) bilinear hoist: U = Ht @ Wbil^T [4096,768], K=384
  gemm_bf16<<<dim3(H_/BN, BE_/BM), dim3(256), 0, stream>>>(
      Hcat + HH_, H_, Wb, (const float*)nullptr, U, H_, BE_, H_, HH_, 0, 0, 0,
      (const float*)nullptr, (const int*)nullptr, 0);

  // 6) batched score GEMM with lin-term epilogue: S [4096, 256] f32
  gemm_S<<<dim3(2, B_), dim3(256), 0, stream>>>(Hcat, U, linHT, b_lin, S);

  // 7) CE gather + reduce
  ce_kernel<<<dim3(B_*R_/256), dim3(256), 0, stream>>>(
      rel_head, rel_tail, rel_label, S, out);
}

// Round 5
// 68.351 us; speedup vs baseline: 6.9125x; 1.1080x over previous
//
#include <hip/hip_runtime.h>
#include <math.h>

typedef unsigned short u16;
typedef __bf16 bf16x8 __attribute__((ext_vector_type(8)));
typedef float f32x4 __attribute__((ext_vector_type(4)));

#define B_ 32
#define W_ 512
#define H_ 768
#define HH_ 384
#define E_ 128
#define R_ 1024
#define BE_ (B_*E_)     /* 4096 */
#define K1_ (2*H_)      /* 1536 */

__device__ __forceinline__ u16 f2bf(float f) {
  unsigned u = __float_as_uint(f);
  u = (u + 0x7fffu + ((u >> 16) & 1u)) >> 16;   // RNE
  return (u16)u;
}
__device__ __forceinline__ float bf2f(u16 u) {
  return __uint_as_float(((unsigned)u) << 16);
}

__device__ __forceinline__ void gload_lds16(const void* g, void* l) {
  __builtin_amdgcn_global_load_lds(
      (__attribute__((address_space(1))) void*)(g),
      (__attribute__((address_space(3))) void*)(l), 16, 0, 0);
}

// bijective XCD-chunked block swizzle (m204)
__device__ __forceinline__ void xcd_swizzle(int& bx, int& by) {
  const int nwg = gridDim.x * gridDim.y;
  int orig = blockIdx.y * gridDim.x + blockIdx.x;
  int q = nwg >> 3, r = nwg & 7;
  int xcd = orig & 7, idx = orig >> 3;
  int wgid = (xcd < r ? xcd * (q + 1) : r * (q + 1) + (xcd - r) * q) + idx;
  bx = wgid % gridDim.x;
  by = wgid / gridDim.x;
}

// ---------------------------------------------------------------------------
// Fused prep: (A) weight->bf16, (B) P table P[l,n]=emb[l].W1[n,768:]+b1[n],
// (C) entity token gather to bf16.
// ---------------------------------------------------------------------------
#define NBLK_W 2017
#define NBLK_P 1152
#define NBLK_X 4096

__global__ __launch_bounds__(256) void prep_all(
    const float* __restrict__ Wh1, const float* __restrict__ Wt1,
    const float* __restrict__ Wh2, const float* __restrict__ Wt2,
    const float* __restrict__ Wbil,
    const float* __restrict__ bh1, const float* __restrict__ bt1,
    const float* __restrict__ bh2, const float* __restrict__ bt2,
    const float* __restrict__ emb,
    const float* __restrict__ hs, const int* __restrict__ ent_start,
    u16* __restrict__ W1c, u16* __restrict__ W2c, u16* __restrict__ Wb,
    float* __restrict__ b2cat, float* __restrict__ P, u16* __restrict__ X)
{
  const int blk = blockIdx.x;
  const int tid = threadIdx.x;

  if (blk < NBLK_W) {
    const int i = blk * 256 + tid;
    const int SW1 = 294912;              // W1c: 1536 rows x 768 cols /4
    const int SW2 = SW1 + 147456;        // W2c: 768x768 /4
    const int SWB = SW2 + 73728;         // Wb:  768x384 /4
    const int SB2 = SWB + 192;           // b2cat: 768 /4
    if (i < SW1) {
      int row = i / 192, c = i % 192;
      const float4* src = (const float4*)((row < 768)
          ? (Wh1 + (size_t)row * K1_) : (Wt1 + (size_t)(row - 768) * K1_));
      float4 v = src[c];
      ushort4 o; o.x = f2bf(v.x); o.y = f2bf(v.y); o.z = f2bf(v.z); o.w = f2bf(v.w);
      ((ushort4*)W1c)[i] = o;
    } else if (i < SW2) {
      int j = i - SW1;
      float4 v = (j < 73728) ? ((const float4*)Wh2)[j]
                             : ((const float4*)Wt2)[j - 73728];
      ushort4 o; o.x = f2bf(v.x); o.y = f2bf(v.y); o.z = f2bf(v.z); o.w = f2bf(v.w);
      ((ushort4*)W2c)[j] = o;
    } else if (i < SWB) {
      int j = i - SW2;
      float4 v = ((const float4*)Wbil)[j];
      ushort4 o; o.x = f2bf(v.x); o.y = f2bf(v.y); o.z = f2bf(v.z); o.w = f2bf(v.w);
      ((ushort4*)Wb)[j] = o;
    } else if (i < SB2) {
      int j = i - SWB;
      ((float4*)b2cat)[j] = (j < 96) ? ((const float4*)bh2)[j]
                                     : ((const float4*)bt2)[j - 96];
    }
  } else if (blk < NBLK_W + NBLK_P) {
    const int w = (blk - NBLK_W) * 4 + (tid >> 6);
    const int lane = tid & 63;
    const int l = w / K1_;
    const int n = w - l * K1_;
    const float* wrow = (n < 768) ? (Wh1 + (size_t)n * K1_ + 768)
                                  : (Wt1 + (size_t)(n - 768) * K1_ + 768);
    const float  bb   = (n < 768) ? bh1[n] : bt1[n - 768];
    const float* ev = emb + (size_t)l * H_;
    float s = 0.f;
#pragma unroll
    for (int t = 0; t < 12; ++t) {
      int d = lane + 64 * t;
      s += ev[d] * wrow[d];
    }
#pragma unroll
    for (int off = 32; off; off >>= 1) s += __shfl_down(s, off);
    if (lane == 0) P[(size_t)l * K1_ + n] = s + bb;
  } else {
    const int be = blk - (NBLK_W + NBLK_P);
    if (tid < 192) {
      int b = be >> 7;
      int start = ent_start[be];
      const float4* s0 = (const float4*)(hs + ((size_t)b * W_ + start) * H_);
      float4 v = s0[tid];
      ushort4 o; o.x = f2bf(v.x); o.y = f2bf(v.y); o.z = f2bf(v.z); o.w = f2bf(v.w);
      ((ushort4*)(X + (size_t)be * H_))[tid] = o;
    }
  }
}

// ---------------------------------------------------------------------------
// bf16 MFMA GEMM, double-buffered 2-phase (T3-min recipe):
// per K-step: STAGE(next buf) || ds_read+MFMA(cur) -> vmcnt(0) -> barrier.
// 128x128 tile, BK=64, 4 waves (2x2). Linear LDS + pre-swizzled source.
// ---------------------------------------------------------------------------
#define BM 128
#define BN 128
#define BKK 64

__global__ __launch_bounds__(256, 2) void gemm_bf16(
    const u16* __restrict__ A, int lda,
    const u16* __restrict__ Wt,              // [N][K] row-major
    const float* __restrict__ bias,
    u16* __restrict__ C, int ldc,
    int M, int N, int K, int do_relu, int half_n, int aoff,
    const float* __restrict__ rowBias,       // P [3][ldP] or null
    const int* __restrict__ rowLabel, int ldP)
{
  __shared__ char smem[2 * 32768];           // [buf][As 16KB | Bs 16KB]

  int bx, by;
  xcd_swizzle(bx, by);
  const int bn = bx * BN;
  const int bm = by * BM;

  const int tid  = threadIdx.x;
  const int wid  = tid >> 6;
  const int lane = tid & 63;
  const int wm = ((wid >> 1) & 1) * 64;
  const int wn = (wid & 1) * 64;

  const int a0 = (half_n && bn >= half_n) ? aoff : 0;

  const int srow = lane >> 3;
  const int sk8  = (lane & 7) ^ srow;
  const u16* gA = A  + (size_t)(bm + 32*wid + srow) * lda + a0 + 8*sk8;
  const u16* gB = Wt + (size_t)(bn + 32*wid + srow) * K  + 8*sk8;

  const int frow = lane & 15;
  const int fk8  = lane >> 4;

  f32x4 acc[4][4] = {};

  auto stage = [&](int buf, int k0) {
    char* As = smem + buf * 32768;
    char* Bs = As + 16384;
#pragma unroll
    for (int i = 0; i < 4; ++i) {
      gload_lds16(gA + k0 + (size_t)i * 8 * lda, As + (4*wid + i) * 1024);
      gload_lds16(gB + k0 + (size_t)i * 8 * K,   Bs + (4*wid + i) * 1024);
    }
  };

  const int nt = K / BKK;
  stage(0, 0);
  asm volatile("s_waitcnt vmcnt(0)" ::: "memory");
  __syncthreads();

  for (int t = 0; t < nt; ++t) {
    const int cur = t & 1;
    if (t + 1 < nt) stage(cur ^ 1, (t + 1) * BKK);

    char* As = smem + cur * 32768;
    char* Bs = As + 16384;
#pragma unroll
    for (int kh = 0; kh < 2; ++kh) {
      bf16x8 a[4], b[4];
#pragma unroll
      for (int m = 0; m < 4; ++m) {
        const int row  = wm + m*16 + frow;
        const int slot = (kh*4 + fk8) ^ (row & 7);
        a[m] = *(const bf16x8*)(As + row*128 + slot*16);
      }
#pragma unroll
      for (int n = 0; n < 4; ++n) {
        const int row  = wn + n*16 + frow;
        const int slot = (kh*4 + fk8) ^ (row & 7);
        b[n] = *(const bf16x8*)(Bs + row*128 + slot*16);
      }
#pragma unroll
      for (int m = 0; m < 4; ++m)
#pragma unroll
        for (int n = 0; n < 4; ++n)
          acc[m][n] = __builtin_amdgcn_mfma_f32_16x16x32_bf16(
              a[m], b[n], acc[m][n], 0, 0, 0);
    }

    if (t + 1 < nt) {
      asm volatile("s_waitcnt vmcnt(0)" ::: "memory");
      __syncthreads();
    }
  }

  int lbl[4][4];
  if (rowLabel) {
#pragma unroll
    for (int m = 0; m < 4; ++m)
#pragma unroll
      for (int r = 0; r < 4; ++r)
        lbl[m][r] = rowLabel[bm + wm + m*16 + fk8*4 + r];
  }

#pragma unroll
  for (int n = 0; n < 4; ++n) {
    const int col = bn + wn + n*16 + frow;
    const float bv = bias ? bias[col] : 0.f;
    float p0 = 0.f, p1 = 0.f, p2 = 0.f;
    if (rowLabel) {
      p0 = rowBias[col];
      p1 = rowBias[ldP + col];
      p2 = rowBias[2*ldP + col];
    }
#pragma unroll
    for (int m = 0; m < 4; ++m) {
#pragma unroll
      for (int r = 0; r < 4; ++r) {
        const int row = bm + wm + m*16 + fk8*4 + r;
        float v = acc[m][n][r] + bv;
        if (rowLabel) {
          int l = lbl[m][r];
          v += (l == 0) ? p0 : ((l == 1) ? p1 : p2);
        }
        if (do_relu) v = fmaxf(v, 0.f);
        C[(size_t)row * ldc + col] = f2bf(v);
      }
    }
  }
}

// ---------------------------------------------------------------------------
// Batched score GEMM, 64x64 tiles (grid 4 x 64 = 256 blocks), double-buffered:
// S[z, e1, e2*2+o] = Hh[z,e1,:] . U[z,e2,o*384:] + linH + linT + b_lin[o]
// ---------------------------------------------------------------------------
__global__ __launch_bounds__(256, 2) void gemm_S(
    const u16* __restrict__ Hcat, const u16* __restrict__ U,
    const float* __restrict__ linHT, const float* __restrict__ b_lin,
    float* __restrict__ S)
{
  __shared__ char smem[2 * 16384];           // [buf][As 8KB | Bs 8KB]

  int bx, by;
  xcd_swizzle(bx, by);
  const int z  = by >> 1;
  const int bm = (by & 1) * 64;
  const int bn = bx * 64;

  const int tid  = threadIdx.x;
  const int wid  = tid >> 6;
  const int lane = tid & 63;
  const int wm = ((wid >> 1) & 1) * 32;
  const int wn = (wid & 1) * 32;

  const int srow = lane >> 3;
  const int sk8  = (lane & 7) ^ srow;
  const u16* gA = Hcat + (size_t)z * 98304 + (size_t)(bm + 16*wid + srow) * 768 + 8*sk8;
  const u16* gB = U    + (size_t)z * 98304 + (size_t)(bn + 16*wid + srow) * 384 + 8*sk8;

  const int frow = lane & 15;
  const int fk8  = lane >> 4;

  f32x4 acc[2][2] = {};

  auto stage = [&](int buf, int k0) {
    char* As = smem + buf * 16384;
    char* Bs = As + 8192;
#pragma unroll
    for (int i = 0; i < 2; ++i) {
      gload_lds16(gA + k0 + (size_t)i * 8 * 768, As + (2*wid + i) * 1024);
      gload_lds16(gB + k0 + (size_t)i * 8 * 384, Bs + (2*wid + i) * 1024);
    }
  };

  const int nt = 384 / BKK;   // 6
  stage(0, 0);
  asm volatile("s_waitcnt vmcnt(0)" ::: "memory");
  __syncthreads();

  for (int t = 0; t < nt; ++t) {
    const int cur = t & 1;
    if (t + 1 < nt) stage(cur ^ 1, (t + 1) * BKK);

    char* As = smem + cur * 16384;
    char* Bs = As + 8192;
#pragma unroll
    for (int kh = 0; kh < 2; ++kh) {
      bf16x8 a[2], b[2];
#pragma unroll
      for (int m = 0; m < 2; ++m) {
        const int row  = wm + m*16 + frow;
        const int slot = (kh*4 + fk8) ^ (row & 7);
        a[m] = *(const bf16x8*)(As + row*128 + slot*16);
      }
#pragma unroll
      for (int n = 0; n < 2; ++n) {
        const int row  = wn + n*16 + frow;
        const int slot = (kh*4 + fk8) ^ (row & 7);
        b[n] = *(const bf16x8*)(Bs + row*128 + slot*16);
      }
#pragma unroll
      for (int m = 0; m < 2; ++m)
#pragma unroll
        for (int n = 0; n < 2; ++n)
          acc[m][n] = __builtin_amdgcn_mfma_f32_16x16x32_bf16(
              a[m], b[n], acc[m][n], 0, 0, 0);
    }

    if (t + 1 < nt) {
      asm volatile("s_waitcnt vmcnt(0)" ::: "memory");
      __syncthreads();
    }
  }

  // epilogue: n_out parity = frow parity (bn, wn, n*16 all even)
  const int o = frow & 1;
  const float blv = b_lin[o];
  float linH[2][4];
#pragma unroll
  for (int m = 0; m < 2; ++m)
#pragma unroll
    for (int r = 0; r < 4; ++r)
      linH[m][r] = linHT[(size_t)(z*128 + bm + wm + m*16 + fk8*4 + r) * 4 + o];

#pragma unroll
  for (int n = 0; n < 2; ++n) {
    const int n_out = bn + wn + n*16 + frow;
    const int e2 = n_out >> 1;
    const float lt = linHT[(size_t)(z*128 + e2) * 4 + 2 + o];
#pragma unroll
    for (int m = 0; m < 2; ++m) {
#pragma unroll
      for (int r = 0; r < 4; ++r) {
        const int row = bm + wm + m*16 + fk8*4 + r;
        S[((size_t)(z*128 + row)) * 256 + n_out] =
            acc[m][n][r] + linH[m][r] + lt + blv;
      }
    }
  }
}

// ---------------------------------------------------------------------------
// per-entity linear terms, grid-strided waves + ushort4 loads.
// block 0 zeroes out[0].
// ---------------------------------------------------------------------------
__global__ __launch_bounds__(256) void lin_parts_kernel(
    const u16* __restrict__ Hcat, const float* __restrict__ W_lin,
    float* __restrict__ linHT, float* __restrict__ out)
{
  if (blockIdx.x == 0 && threadIdx.x == 0) out[0] = 0.f;
  const int wave = blockIdx.x * 4 + (threadIdx.x >> 6);
  const int lane = threadIdx.x & 63;
  const int nwave = gridDim.x * 4;

  for (int be = wave; be < BE_; be += nwave) {
    const ushort4* src = (const ushort4*)(Hcat + (size_t)be * 768);
    float s0 = 0.f, s1 = 0.f, s2 = 0.f, s3 = 0.f;
#pragma unroll
    for (int rd = 0; rd < 3; ++rd) {
      const int idx4 = rd * 64 + lane;      // 0..191
      const int c = idx4 * 4;               // col 0..764
      ushort4 v4 = src[idx4];
      float4 w0 = *(const float4*)(W_lin + c);
      float4 w1 = *(const float4*)(W_lin + 768 + c);
      float d0 = bf2f(v4.x)*w0.x + bf2f(v4.y)*w0.y + bf2f(v4.z)*w0.z + bf2f(v4.w)*w0.w;
      float d1 = bf2f(v4.x)*w1.x + bf2f(v4.y)*w1.y + bf2f(v4.z)*w1.z + bf2f(v4.w)*w1.w;
      if (c < 384) { s0 += d0; s1 += d1; }
      else         { s2 += d0; s3 += d1; }
    }
#pragma unroll
    for (int off = 32; off; off >>= 1) {
      s0 += __shfl_down(s0, off);
      s1 += __shfl_down(s1, off);
      s2 += __shfl_down(s2, off);
      s3 += __shfl_down(s3, off);
    }
    if (lane == 0) {
      float4 v = {s0, s1, s2, s3};
      *(float4*)(linHT + (size_t)be * 4) = v;
    }
  }
}

// ---------------------------------------------------------------------------
// CE over precomputed logits S: one thread per relation
// ---------------------------------------------------------------------------
__global__ __launch_bounds__(256) void ce_kernel(
    const int* __restrict__ rel_head, const int* __restrict__ rel_tail,
    const int* __restrict__ rel_label, const float* __restrict__ S,
    float* __restrict__ out)
{
  const int i = blockIdx.x * 256 + threadIdx.x;
  const int b  = i >> 10;
  const int rh = rel_head[i];
  const int rt = rel_tail[i];
  const int lab = rel_label[i];
  const float2 lv = *(const float2*)(S + ((size_t)(b*E_ + rh)) * 256 + rt*2);
  const float l0 = lv.x, l1 = lv.y;
  const float m = fmaxf(l0, l1);
  const float lse = m + logf(expf(l0 - m) + expf(l1 - m));
  float nll = lse - (lab == 0 ? l0 : l1);

#pragma unroll
  for (int off = 32; off; off >>= 1) nll += __shfl_down(nll, off);
  __shared__ float red[4];
  if ((threadIdx.x & 63) == 0) red[threadIdx.x >> 6] = nll;
  __syncthreads();
  if (threadIdx.x == 0)
    atomicAdd(out, (red[0] + red[1] + red[2] + red[3]) * (1.0f / R_));
}

// ---------------------------------------------------------------------------
extern "C" void kernel_launch(void* const* d_in, const int* in_sizes, int n_in,
                              void* d_out, int out_size, void* d_ws, size_t ws_size,
                              hipStream_t stream)
{
  const float* hs        = (const float*)d_in[0];
  const int*   rel_head  = (const int*)  d_in[1];
  const int*   rel_tail  = (const int*)  d_in[2];
  const int*   rel_label = (const int*)  d_in[3];
  const int*   ent_start = (const int*)  d_in[4];
  const int*   ent_label = (const int*)  d_in[6];
  const float* emb   = (const float*)d_in[7];
  const float* Wh1   = (const float*)d_in[8];
  const float* bh1   = (const float*)d_in[9];
  const float* Wh2   = (const float*)d_in[10];
  const float* bh2   = (const float*)d_in[11];
  const float* Wt1   = (const float*)d_in[12];
  const float* bt1   = (const float*)d_in[13];
  const float* Wt2   = (const float*)d_in[14];
  const float* bt2   = (const float*)d_in[15];
  const float* W_bil = (const float*)d_in[16];
  const float* W_lin = (const float*)d_in[17];
  const float* b_lin = (const float*)d_in[18];
  float* out = (float*)d_out;

  // workspace layout
  u16* X    = (u16*)d_ws;                 // 4096*768
  u16* H1   = X    + (size_t)BE_ * H_;    // 4096*1536
  u16* Hcat = H1   + (size_t)BE_ * K1_;   // 4096*768
  u16* U    = Hcat + (size_t)BE_ * H_;    // 4096*768
  u16* W1c  = U    + (size_t)BE_ * H_;    // 1536*768
  u16* W2c  = W1c  + (size_t)K1_ * H_;    // 768*768
  u16* Wb   = W2c  + (size_t)H_ * H_;     // 768*384
  float* b2cat = (float*)(Wb + (size_t)H_ * HH_);  // 768
  float* P     = b2cat + H_;                       // 3*1536
  float* linHT = P + 3*K1_;                        // 4096*4
  float* S     = linHT + 4*BE_;                    // 4096*256

  // 1) fused prep
  prep_all<<<dim3(NBLK_W + NBLK_P + NBLK_X), dim3(256), 0, stream>>>(
      Wh1, Wt1, Wh2, Wt2, W_bil, bh1, bt1, bh2, bt2, emb,
      hs, ent_start, W1c, W2c, Wb, b2cat, P, X);

  // 2) layer-1 GEMM: H1 = relu(X @ W1c^T + P[label]) [4096,1536], K=768
  gemm_bf16<<<dim3(K1_/BN, BE_/BM), dim3(256), 0, stream>>>(
      X, H_, W1c, (const float*)nullptr, H1, K1_, BE_, K1_, H_, 1, 0, 0,
      P, ent_label, K1_);

  // 3) layer-2 fused GEMM: Hcat = relu([H1h@Wh2^T ; H1t@Wt2^T] + b2cat) [4096,768]
  gemm_bf16<<<dim3(H_/BN, BE_/BM), dim3(256), 0, stream>>>(
      H1, K1_, W2c, b2cat, Hcat, H_, BE_, H_, H_, 1, HH_, H_,
      (const float*)nullptr, (const int*)nullptr, 0);

  // 4) per-entity linear terms (+ zero out)
  lin_parts_kernel<<<dim3(128), dim3(256), 0, stream>>>(Hcat, W_lin, linHT, out);

  // 5) bilinear hoist: U = Ht @ Wbil^T [4096,768], K=384
  gemm_bf16<<<dim3(H_/BN, BE_/BM), dim3(256), 0, stream>>>(
      Hcat + HH_, H_, Wb, (const float*)nullptr, U, H_, BE_, H_, HH_, 0, 0, 0,
      (const float*)nullptr, (const int*)nullptr, 0);

  // 6) batched score GEMM with lin-term epilogue: S [4096, 256] f32
  gemm_S<<<dim3(4, 2*B_), dim3(256), 0, stream>>>(Hcat, U, linHT, b_lin, S);

  // 7) CE gather + reduce
  ce_kernel<<<dim3(B_*R_/256), dim3(256), 0, stream>>>(
      rel_head, rel_tail, rel_label, S, out);
}